// Round 6
// baseline (1847.747 us; speedup 1.0000x reference)
//
#include <hip/hip_runtime.h>
#include <stdint.h>

typedef float4 __attribute__((may_alias)) float4a;
typedef unsigned int u32;
typedef unsigned long long u64;

// ws float layout: [0] loss, [1] sum(ema_cs),
// [16,16+K) e2 | [16+K,+K) counts | [16+2K,+K*64) emb sums | then N u64 slots
#define WS_LOSS 0
#define WS_SEMA 1
#define WS_HDR  16
#define TK 64

__global__ void k_sig(float* o, float v) { o[0] = v; }

__device__ __forceinline__ float sq_nofuse(float x) {
  float p = x * x;
  __asm__("" : "+v"(p));   // block ffp-contract fusing (numpy rounds the square)
  return p;
}

// numpy pairwise_sum of squares, n=64 contiguous fp32: 8 accumulators + fixed
// combine tree, STREAMING (only ~16 live temps -> no spill).
__device__ __forceinline__ float z2_np64(const float* v) {
  float r0 = sq_nofuse(v[0]), r1 = sq_nofuse(v[1]);
  float r2 = sq_nofuse(v[2]), r3 = sq_nofuse(v[3]);
  float r4 = sq_nofuse(v[4]), r5 = sq_nofuse(v[5]);
  float r6 = sq_nofuse(v[6]), r7 = sq_nofuse(v[7]);
  #pragma unroll
  for (int i = 8; i < 64; i += 8) {
    r0 += sq_nofuse(v[i + 0]); r1 += sq_nofuse(v[i + 1]);
    r2 += sq_nofuse(v[i + 2]); r3 += sq_nofuse(v[i + 3]);
    r4 += sq_nofuse(v[i + 4]); r5 += sq_nofuse(v[i + 5]);
    r6 += sq_nofuse(v[i + 6]); r7 += sq_nofuse(v[i + 7]);
  }
  return ((r0 + r1) + (r2 + r3)) + ((r4 + r5) + (r6 + r7));
}

// async 16B-per-lane DMA: global -> LDS (wave-uniform LDS base + lane*16)
__device__ __forceinline__ void dma16(const float* g, float* l) {
  __builtin_amdgcn_global_load_lds(
      (const __attribute__((address_space(1))) unsigned int*)g,
      (__attribute__((address_space(3))) unsigned int*)l,
      16, 0, 0);
}

__global__ __launch_bounds__(256) void k_prep(const float* __restrict__ cb,
                                              const float* __restrict__ ecs,
                                              float* __restrict__ ws, int K) {
  const int k = blockIdx.x * 256 + threadIdx.x;   // grid covers exactly K rows
  const float* e = cb + ((size_t)k << 6);
  ws[WS_HDR + k] = z2_np64(e);                    // e2[k], np-fp32-exact

  float v = ecs[k];
  #pragma unroll
  for (int o = 32; o; o >>= 1) v += __shfl_xor(v, o, 64);
  if ((threadIdx.x & 63) == 0) atomicAdd(&ws[WS_SEMA], v);
}

// distance scan: 3 z-rows per lane (R=3 -> LDS broadcast bus at 67% of VALU,
// breaking the R=2 LDS/VALU balance that capped R0/R4 at ~60% issue).
// Eighth of K per block; async global_load_lds double-buffer (verified R4 path).
// NO min-waves launch bound (toolchain caps arch-VGPRs at 256/min_waves -> spill).
__global__ __launch_bounds__(256) void k_main(const float* __restrict__ z,
                                              const float* __restrict__ cb,
                                              const float* __restrict__ e2s,
                                              u64* __restrict__ slots,
                                              int N, int K) {
  __shared__ float se[2][TK * 64];
  __shared__ float se2[2][TK];

  const int tid = threadIdx.x;
  const int lane = tid & 63;
  const int wave = tid >> 6;
  const int eighth = blockIdx.x & 7;              // K-eighth this block scans
  const int rowblk = blockIdx.x >> 3;             // 768 rows per row-block
  const int r0 = rowblk * 768 + tid;
  const int r1 = r0 + 256;
  const int r2 = r0 + 512;
  const int eK = K >> 3;
  const int kbase = eighth * eK;

  // tail clamp: 768 does not divide N; invalid rows load row N-1, stores guarded
  const int r1c = (r1 < N) ? r1 : (N - 1);
  const int r2c = (r2 < N) ? r2 : (N - 1);

  float zv0[64], zv1[64], zv2[64];
  {
    const float4a* zr0 = (const float4a*)(z + ((size_t)r0 << 6));
    const float4a* zr1 = (const float4a*)(z + ((size_t)r1c << 6));
    const float4a* zr2 = (const float4a*)(z + ((size_t)r2c << 6));
    #pragma unroll
    for (int t = 0; t < 16; ++t) {
      const float4 a = zr0[t];
      zv0[4*t] = a.x; zv0[4*t+1] = a.y; zv0[4*t+2] = a.z; zv0[4*t+3] = a.w;
      const float4 b = zr1[t];
      zv1[4*t] = b.x; zv1[4*t+1] = b.y; zv1[4*t+2] = b.z; zv1[4*t+3] = b.w;
      const float4 c = zr2[t];
      zv2[4*t] = c.x; zv2[4*t+1] = c.y; zv2[4*t+2] = c.z; zv2[4*t+3] = c.w;
    }
  }
  const float z20 = z2_np64(zv0);
  const float z21 = z2_np64(zv1);
  const float z22 = z2_np64(zv2);

  const int nt = eK / TK;
  const int seg = wave * 4;                       // 4 x 1KB segments per wave
  {  // prologue: DMA tile 0 (e rows + e2) into buffer 0
    const float* src = cb + ((size_t)kbase << 6) + (size_t)seg * 256 + lane * 4;
    float* dst = se[0] + seg * 256;
    #pragma unroll
    for (int c = 0; c < 4; ++c) dma16(src + c * 256, dst + c * 256);
    if (tid < 16) dma16(e2s + kbase + tid * 4, se2[0]);
  }

  float best0 = 3.0e38f, best1 = 3.0e38f, best2 = 3.0e38f;
  int bk0 = 0, bk1 = 0, bk2 = 0;

  for (int t = 0; t < nt; ++t) {
    const int b = t & 1;
    __syncthreads();   // implicit vmcnt(0) drain: buf[b] DMA (issued a full tile ago)

    if (t + 1 < nt) {  // issue next tile's DMA into the other buffer
      const int ktile = kbase + (t + 1) * TK;
      const float* src = cb + ((size_t)ktile << 6) + (size_t)seg * 256 + lane * 4;
      float* dst = se[b ^ 1] + seg * 256;
      #pragma unroll
      for (int c = 0; c < 4; ++c) dma16(src + c * 256, dst + c * 256);
      if (tid < 16) dma16(e2s + ktile + tid * 4, se2[b ^ 1]);
    }

    const float* __restrict__ eb  = se[b];
    const float* __restrict__ e2b = se2[b];
    const int k0 = kbase + t * TK;
    for (int kk = 0; kk < TK; kk += 2) {
      const float* e0 = eb + (kk << 6);
      const float* e1 = e0 + 64;
      float g00 = 0.f, g10 = 0.f, g20 = 0.f;
      float g01 = 0.f, g11 = 0.f, g21 = 0.f;
      #pragma unroll
      for (int j = 0; j < 64; ++j) {     // ascending-j fused chains (np/BLAS order)
        const float ej0 = e0[j];
        const float ej1 = e1[j];
        g00 = __builtin_fmaf(ej0, zv0[j], g00);
        g10 = __builtin_fmaf(ej0, zv1[j], g10);
        g20 = __builtin_fmaf(ej0, zv2[j], g20);
        g01 = __builtin_fmaf(ej1, zv0[j], g01);
        g11 = __builtin_fmaf(ej1, zv1[j], g11);
        g21 = __builtin_fmaf(ej1, zv2[j], g21);
      }
      const float ea = e2b[kk], ebv = e2b[kk + 1];
      // per row: k then k+1, strict < : first-min-wins (exact R0 arithmetic)
      const float d00 = __builtin_fmaf(-2.0f, g00, z20 + ea);
      if (d00 < best0) { best0 = d00; bk0 = k0 + kk; }
      const float d01 = __builtin_fmaf(-2.0f, g01, z20 + ebv);
      if (d01 < best0) { best0 = d01; bk0 = k0 + kk + 1; }
      const float d10 = __builtin_fmaf(-2.0f, g10, z21 + ea);
      if (d10 < best1) { best1 = d10; bk1 = k0 + kk; }
      const float d11 = __builtin_fmaf(-2.0f, g11, z21 + ebv);
      if (d11 < best1) { best1 = d11; bk1 = k0 + kk + 1; }
      const float d20 = __builtin_fmaf(-2.0f, g20, z22 + ea);
      if (d20 < best2) { best2 = d20; bk2 = k0 + kk; }
      const float d21 = __builtin_fmaf(-2.0f, g21, z22 + ebv);
      if (d21 < best2) { best2 = d21; bk2 = k0 + kk + 1; }
    }
  }

  // merge eighths: smaller d wins; equal d -> smaller k (low 32 bits) = first-win
  atomicMin(&slots[r0], ((u64)__float_as_uint(best0) << 32) | (u32)bk0);
  if (r1 < N) atomicMin(&slots[r1], ((u64)__float_as_uint(best1) << 32) | (u32)bk1);
  if (r2 < N) atomicMin(&slots[r2], ((u64)__float_as_uint(best2) << 32) | (u32)bk2);
}

// epilogue: read winner, write index+quantized, loss, EMA scatter
__global__ __launch_bounds__(256) void k_post(const float* __restrict__ z,
                                              const float* __restrict__ cb,
                                              const u64* __restrict__ slots,
                                              float* __restrict__ ws,
                                              float* __restrict__ o,
                                              int N, int K) {
  const int r = blockIdx.x * 256 + threadIdx.x;
  const int bk = (int)(u32)(slots[r] & 0xFFFFFFFFull);
  const size_t base = (size_t)N << 6;
  o[base + 1 + (size_t)r] = (float)bk;

  const float4a* zr = (const float4a*)(z + ((size_t)r << 6));
  const float4a* qr = (const float4a*)(cb + ((size_t)bk << 6));
  float4a* dst = (float4a*)(o + ((size_t)r << 6));
  float zbuf[64];
  float lsum = 0.f;
  #pragma unroll
  for (int t = 0; t < 16; ++t) {
    const float4 zw = zr[t];
    const float4 qw = qr[t];
    float4 out;
    float d;
    d = zw.x - qw.x; lsum = __builtin_fmaf(d, d, lsum); out.x = zw.x + (qw.x - zw.x);
    d = zw.y - qw.y; lsum = __builtin_fmaf(d, d, lsum); out.y = zw.y + (qw.y - zw.y);
    d = zw.z - qw.z; lsum = __builtin_fmaf(d, d, lsum); out.z = zw.z + (qw.z - zw.z);
    d = zw.w - qw.w; lsum = __builtin_fmaf(d, d, lsum); out.w = zw.w + (qw.w - zw.w);
    dst[t] = out;
    zbuf[4*t] = zw.x; zbuf[4*t+1] = zw.y; zbuf[4*t+2] = zw.z; zbuf[4*t+3] = zw.w;
  }

  #pragma unroll
  for (int s = 32; s; s >>= 1) lsum += __shfl_xor(lsum, s, 64);
  if ((threadIdx.x & 63) == 0) atomicAdd(ws + WS_LOSS, lsum);

  atomicAdd(ws + WS_HDR + K + bk, 1.0f);
  float* emb = ws + WS_HDR + 2 * K + ((size_t)bk << 6);
  #pragma unroll
  for (int j = 0; j < 64; ++j) atomicAdd(emb + j, zbuf[j]);
}

__global__ __launch_bounds__(256) void k_fin(const float* __restrict__ ecs,
                                             const float* __restrict__ ees,
                                             const float* __restrict__ ws,
                                             float* __restrict__ o,
                                             int N, int K, float lossmul) {
  const int KD = K << 6;
  const int idx = blockIdx.x * 256 + threadIdx.x;
  if (idx >= KD) return;
  const int k = idx >> 6;
  const int j = idx & 63;
  const size_t base = (size_t)N << 6;

  const float n = 0.99f * ws[WS_SEMA] + 0.01f * (float)N;
  const float cs_new = 0.99f * ecs[k] + 0.01f * ws[WS_HDR + K + k];
  const float smoothed = (cs_new + 1e-5f) / (n + (float)K * 1e-5f) * n;
  const float es_new = 0.99f * ees[idx] + 0.01f * ws[WS_HDR + 2 * K + idx];

  const size_t es_base = base + 1 + (size_t)N + (size_t)K;
  o[es_base + (size_t)idx] = es_new;
  o[es_base + (size_t)KD + (size_t)idx] = es_new / smoothed;
  if (j == 0)   o[base + 1 + (size_t)N + (size_t)k] = cs_new;
  if (idx == 0) o[base] = ws[WS_LOSS] * lossmul;
}

extern "C" void kernel_launch(void* const* d_in, const int* in_sizes, int n_in,
                              void* d_out, int out_size, void* d_ws, size_t ws_size,
                              hipStream_t stream) {
  float* o = (float*)d_out;
  const float* z   = (const float*)d_in[0];
  const float* cb  = (const float*)d_in[1];
  const float* ecs = (const float*)d_in[2];
  const float* ees = (const float*)d_in[3];
  float* ws = (float*)d_ws;

  const long long ND  = (n_in > 0) ? (long long)in_sizes[0] : 0;
  const long long KD  = (n_in > 1) ? (long long)in_sizes[1] : 0;
  const long long K   = (n_in > 2) ? (long long)in_sizes[2] : 0;
  const long long KD2 = (n_in > 3) ? (long long)in_sizes[3] : 0;
  const long long D   = (K > 0) ? KD / K : 0;
  const long long N   = (D > 0) ? ND / D : 0;

  const long long ws_floats = 16 + 2 * K + KD + 2 * N;  // slots = N u64 at tail

  float sig = 0.f;
  if (n_in != 4)                          sig = 1e4f * (float)n_in;
  else if (K <= 0 || KD % K != 0)         sig = 2.5e7f;
  else if (D != 64)                       sig = 1e7f + 1e4f * (float)D;
  else if (KD2 != KD)                     sig = 2e7f;
  else if (ND % 64 != 0 || N % 512 != 0)  sig = 3e7f;
  else if (K % 512 != 0)                  sig = 5e7f;
  else if ((long long)out_size != ND + 1 + N + K + 2 * KD)
                                          sig = (float)out_size;
  else if (ws_size < (size_t)ws_floats * sizeof(float))
                                          sig = 7e6f;
  if (sig != 0.f) { k_sig<<<1, 1, 0, stream>>>(o, sig); return; }

  u64* slots = (u64*)(ws + 16 + 2 * K + KD);      // 8-byte aligned offset
  const float lossmul = (float)(0.25 / (double)ND);
  const long long nrb = (N + 767) / 768;          // row-blocks of 768 (tail-masked)

  hipMemsetAsync(ws, 0, (size_t)(16 + 2 * K + KD) * sizeof(float), stream);
  hipMemsetAsync(slots, 0xFF, (size_t)N * sizeof(u64), stream);
  k_prep<<<(int)(K / 256), 256, 0, stream>>>(cb, ecs, ws, (int)K);
  k_main<<<(int)(8 * nrb), 256, 0, stream>>>(z, cb, ws + WS_HDR, slots, (int)N, (int)K);
  k_post<<<(int)(N / 256), 256, 0, stream>>>(z, cb, slots, ws, o, (int)N, (int)K);
  k_fin<<<(int)(KD / 256), 256, 0, stream>>>(ecs, ees, ws, o, (int)N, (int)K, lossmul);
}

// Round 7
// 1450.355 us; speedup vs baseline: 1.2740x; 1.2740x over previous
//
#include <hip/hip_runtime.h>
#include <stdint.h>

typedef float4 __attribute__((may_alias)) float4a;
typedef float2 __attribute__((may_alias)) float2a;
typedef unsigned int u32;
typedef unsigned long long u64;

// ws float layout: [0] loss, [1] sum(ema_cs),
// [16,16+K) e2 | [16+K,+K) counts | [16+2K,+K*64) emb sums | then N u64 slots
#define WS_LOSS 0
#define WS_SEMA 1
#define WS_HDR  16

__global__ void k_sig(float* o, float v) { o[0] = v; }

__device__ __forceinline__ float sq_nofuse(float x) {
  float p = x * x;
  __asm__("" : "+v"(p));   // block ffp-contract fusing (numpy rounds the square)
  return p;
}

// numpy pairwise_sum of squares, n=64 contiguous fp32: 8 accumulators + fixed
// combine tree, STREAMING (only ~16 live temps -> no spill).
__device__ __forceinline__ float z2_np64(const float* v) {
  float r0 = sq_nofuse(v[0]), r1 = sq_nofuse(v[1]);
  float r2 = sq_nofuse(v[2]), r3 = sq_nofuse(v[3]);
  float r4 = sq_nofuse(v[4]), r5 = sq_nofuse(v[5]);
  float r6 = sq_nofuse(v[6]), r7 = sq_nofuse(v[7]);
  #pragma unroll
  for (int i = 8; i < 64; i += 8) {
    r0 += sq_nofuse(v[i + 0]); r1 += sq_nofuse(v[i + 1]);
    r2 += sq_nofuse(v[i + 2]); r3 += sq_nofuse(v[i + 3]);
    r4 += sq_nofuse(v[i + 4]); r5 += sq_nofuse(v[i + 5]);
    r6 += sq_nofuse(v[i + 6]); r7 += sq_nofuse(v[i + 7]);
  }
  return ((r0 + r1) + (r2 + r3)) + ((r4 + r5) + (r6 + r7));
}

__global__ __launch_bounds__(256) void k_prep(const float* __restrict__ cb,
                                              const float* __restrict__ ecs,
                                              float* __restrict__ ws, int K) {
  const int k = blockIdx.x * 256 + threadIdx.x;   // grid covers exactly K rows
  const float* e = cb + ((size_t)k << 6);
  ws[WS_HDR + k] = z2_np64(e);                    // e2[k], np-fp32-exact

  float v = ecs[k];
  #pragma unroll
  for (int o = 32; o; o >>= 1) v += __shfl_xor(v, o, 64);
  if ((threadIdx.x & 63) == 0) atomicAdd(&ws[WS_SEMA], v);
}

// GEMM-fragment distance scan. Block = 64 rows; 4 waves quarter K.
// Lane (a,b) owns an 8-row x 4-code fragment (32 acc). Per j: 3 ds_read_b128
// (8-way broadcast, bank-free) feed 32 FMAs. Wave-private e-buffers, transposed
// reg->LDS staging; NO __syncthreads in the main loop (one barrier total).
__global__ __launch_bounds__(256) void k_main(const float* __restrict__ z,
                                              const float* __restrict__ cb,
                                              const float* __restrict__ e2s,
                                              u64* __restrict__ slots,
                                              int N, int K) {
  __shared__ float zT[64][64];          // zT[j][row]
  __shared__ float z2p[64][4];          // per-row partial pair-sums s0..s3
  __shared__ float eb[4][64][32];       // per-wave eT[j][code]

  const int tid  = threadIdx.x;
  const int lane = tid & 63;
  const int w    = tid >> 6;
  const int a8   = (lane & 7) * 8;      // fragment row offset
  const int b4   = (lane >> 3) * 4;     // fragment code offset
  const int rowbase = blockIdx.x * 64;
  const int qK  = K >> 2;
  const int k00 = w * qK;               // this wave's K-range
  const int nt  = qK >> 5;              // tiles of 32 codes

  // ---- z-tile stage + transpose: thread t covers row (t&63), j-quarter (t>>6)
  {
    const int r  = tid & 63;
    const int jb = (tid >> 6) * 16;
    const float4a* src = (const float4a*)(z + ((size_t)(rowbase + r) << 6) + jb);
    const float4 v0 = src[0], v1 = src[1], v2 = src[2], v3 = src[3];
    zT[jb + 0][r]  = v0.x; zT[jb + 1][r]  = v0.y; zT[jb + 2][r]  = v0.z; zT[jb + 3][r]  = v0.w;
    zT[jb + 4][r]  = v1.x; zT[jb + 5][r]  = v1.y; zT[jb + 6][r]  = v1.z; zT[jb + 7][r]  = v1.w;
    zT[jb + 8][r]  = v2.x; zT[jb + 9][r]  = v2.y; zT[jb + 10][r] = v2.z; zT[jb + 11][r] = v2.w;
    zT[jb + 12][r] = v3.x; zT[jb + 13][r] = v3.y; zT[jb + 14][r] = v3.z; zT[jb + 15][r] = v3.w;
  }
  // ---- z2 partials: thread t computes np-tree accumulators r_{2q},r_{2q+1}
  // (q = t>>6) for row (t&63); s_q = r_{2q}+r_{2q+1}. Final combine
  // (s0+s1)+(s2+s3) reproduces z2_np64's tree bit-exactly.
  {
    const int r = tid & 63;
    const int q = tid >> 6;
    const float* vr = z + ((size_t)(rowbase + r) << 6) + 2 * q;
    float ra = sq_nofuse(vr[0]), rb = sq_nofuse(vr[1]);
    #pragma unroll
    for (int i = 8; i < 64; i += 8) {
      ra += sq_nofuse(vr[i]); rb += sq_nofuse(vr[i + 1]);
    }
    z2p[r][q] = ra + rb;
  }
  __syncthreads();                      // the only block barrier

  // ---- per-lane row constants
  float z2r[8];
  {
    #pragma unroll
    for (int r = 0; r < 8; ++r) {
      const float4 p = *(const float4a*)&z2p[a8 + r][0];
      z2r[r] = (p.x + p.y) + (p.z + p.w);
    }
  }

  float best[8]; int bk[8];
  #pragma unroll
  for (int r = 0; r < 8; ++r) { best[r] = 3.0e38f; bk[r] = 0; }

  // ---- staging geometry: lane covers code sc (0..31), j-half jh (0 or 32);
  // loads 128 contiguous bytes of cb per tile, writes transposed into eb[w].
  const int sc = lane >> 1;
  const int jh = (lane & 1) * 32;
  const float* cbw = cb + ((size_t)(k00 + sc) << 6) + jh;
  float* __restrict__ myeb = &eb[w][0][0];

  float4 st[8];
  {
    const float4a* sp = (const float4a*)cbw;
    #pragma unroll
    for (int i = 0; i < 8; ++i) st[i] = sp[i];
  }

  for (int t = 0; t < nt; ++t) {
    // transposed e-stage: eT[jh+4i+dj][sc]  (2 lanes/bank -> conflict-free)
    #pragma unroll
    for (int i = 0; i < 8; ++i) {
      float* dp = myeb + (jh + i * 4) * 32 + sc;
      dp[0] = st[i].x; dp[32] = st[i].y; dp[64] = st[i].z; dp[96] = st[i].w;
    }
    if (t + 1 < nt) {                   // prefetch next tile under the j-loop
      const float4a* sp = (const float4a*)(cbw + (size_t)(t + 1) * 2048);
      #pragma unroll
      for (int i = 0; i < 8; ++i) st[i] = sp[i];
    }
    const float4 e2v = *(const float4a*)(e2s + k00 + t * 32 + b4);  // L1/L2-hot

    float acc[8][4];
    #pragma unroll
    for (int r = 0; r < 8; ++r)
      #pragma unroll
      for (int c = 0; c < 4; ++c) acc[r][c] = 0.f;

    #pragma unroll 8
    for (int j = 0; j < 64; ++j) {
      const float4 zlo = *(const float4a*)&zT[j][a8];
      const float4 zhi = *(const float4a*)&zT[j][a8 + 4];
      const float4 ef  = *(const float4a*)&myeb[j * 32 + b4];
      const float zr[8] = {zlo.x, zlo.y, zlo.z, zlo.w, zhi.x, zhi.y, zhi.z, zhi.w};
      const float ec[4] = {ef.x, ef.y, ef.z, ef.w};
      #pragma unroll
      for (int r = 0; r < 8; ++r)
        #pragma unroll
        for (int c = 0; c < 4; ++c)   // ascending-j fma chain per (r,c) = np/BLAS
          acc[r][c] = __builtin_fmaf(ec[c], zr[r], acc[r][c]);
    }

    // selection: lane's codes ascend (c, then tiles) -> strict < = first-min-wins
    const float e2a[4] = {e2v.x, e2v.y, e2v.z, e2v.w};
    const int kt = k00 + t * 32 + b4;
    #pragma unroll
    for (int c = 0; c < 4; ++c) {
      const float e2c = e2a[c];
      const int kk = kt + c;
      #pragma unroll
      for (int r = 0; r < 8; ++r) {
        const float d = __builtin_fmaf(-2.0f, acc[r][c], z2r[r] + e2c);
        if (d < best[r]) { best[r] = d; bk[r] = kk; }
      }
    }
  }

  // ---- cross-lane merge over the 8 col-groups (lanes a, a+8, .., a+56):
  // lexicographic (d, k): equal d -> smaller k (global first-min)
  #pragma unroll
  for (int off = 8; off <= 32; off <<= 1) {
    #pragma unroll
    for (int r = 0; r < 8; ++r) {
      const float pd = __shfl_xor(best[r], off, 64);
      const int   pk = __shfl_xor(bk[r], off, 64);
      if (pd < best[r] || (pd == best[r] && pk < bk[r])) { best[r] = pd; bk[r] = pk; }
    }
  }
  // ---- cross-wave merge via packed atomicMin (distances > 0)
  if ((lane >> 3) == 0) {
    #pragma unroll
    for (int r = 0; r < 8; ++r) {
      atomicMin(&slots[rowbase + a8 + r],
                ((u64)__float_as_uint(best[r]) << 32) | (u32)bk[r]);
    }
  }
}

// epilogue: read winner, write index+quantized, loss, EMA scatter
__global__ __launch_bounds__(256) void k_post(const float* __restrict__ z,
                                              const float* __restrict__ cb,
                                              const u64* __restrict__ slots,
                                              float* __restrict__ ws,
                                              float* __restrict__ o,
                                              int N, int K) {
  const int r = blockIdx.x * 256 + threadIdx.x;
  const int bk = (int)(u32)(slots[r] & 0xFFFFFFFFull);
  const size_t base = (size_t)N << 6;
  o[base + 1 + (size_t)r] = (float)bk;

  const float4a* zr = (const float4a*)(z + ((size_t)r << 6));
  const float4a* qr = (const float4a*)(cb + ((size_t)bk << 6));
  float4a* dst = (float4a*)(o + ((size_t)r << 6));
  float zbuf[64];
  float lsum = 0.f;
  #pragma unroll
  for (int t = 0; t < 16; ++t) {
    const float4 zw = zr[t];
    const float4 qw = qr[t];
    float4 out;
    float d;
    d = zw.x - qw.x; lsum = __builtin_fmaf(d, d, lsum); out.x = zw.x + (qw.x - zw.x);
    d = zw.y - qw.y; lsum = __builtin_fmaf(d, d, lsum); out.y = zw.y + (qw.y - zw.y);
    d = zw.z - qw.z; lsum = __builtin_fmaf(d, d, lsum); out.z = zw.z + (qw.z - zw.z);
    d = zw.w - qw.w; lsum = __builtin_fmaf(d, d, lsum); out.w = zw.w + (qw.w - zw.w);
    dst[t] = out;
    zbuf[4*t] = zw.x; zbuf[4*t+1] = zw.y; zbuf[4*t+2] = zw.z; zbuf[4*t+3] = zw.w;
  }

  #pragma unroll
  for (int s = 32; s; s >>= 1) lsum += __shfl_xor(lsum, s, 64);
  if ((threadIdx.x & 63) == 0) atomicAdd(ws + WS_LOSS, lsum);

  atomicAdd(ws + WS_HDR + K + bk, 1.0f);
  float* emb = ws + WS_HDR + 2 * K + ((size_t)bk << 6);
  #pragma unroll
  for (int j = 0; j < 64; ++j) atomicAdd(emb + j, zbuf[j]);
}

__global__ __launch_bounds__(256) void k_fin(const float* __restrict__ ecs,
                                             const float* __restrict__ ees,
                                             const float* __restrict__ ws,
                                             float* __restrict__ o,
                                             int N, int K, float lossmul) {
  const int KD = K << 6;
  const int idx = blockIdx.x * 256 + threadIdx.x;
  if (idx >= KD) return;
  const int k = idx >> 6;
  const int j = idx & 63;
  const size_t base = (size_t)N << 6;

  const float n = 0.99f * ws[WS_SEMA] + 0.01f * (float)N;
  const float cs_new = 0.99f * ecs[k] + 0.01f * ws[WS_HDR + K + k];
  const float smoothed = (cs_new + 1e-5f) / (n + (float)K * 1e-5f) * n;
  const float es_new = 0.99f * ees[idx] + 0.01f * ws[WS_HDR + 2 * K + idx];

  const size_t es_base = base + 1 + (size_t)N + (size_t)K;
  o[es_base + (size_t)idx] = es_new;
  o[es_base + (size_t)KD + (size_t)idx] = es_new / smoothed;
  if (j == 0)   o[base + 1 + (size_t)N + (size_t)k] = cs_new;
  if (idx == 0) o[base] = ws[WS_LOSS] * lossmul;
}

extern "C" void kernel_launch(void* const* d_in, const int* in_sizes, int n_in,
                              void* d_out, int out_size, void* d_ws, size_t ws_size,
                              hipStream_t stream) {
  float* o = (float*)d_out;
  const float* z   = (const float*)d_in[0];
  const float* cb  = (const float*)d_in[1];
  const float* ecs = (const float*)d_in[2];
  const float* ees = (const float*)d_in[3];
  float* ws = (float*)d_ws;

  const long long ND  = (n_in > 0) ? (long long)in_sizes[0] : 0;
  const long long KD  = (n_in > 1) ? (long long)in_sizes[1] : 0;
  const long long K   = (n_in > 2) ? (long long)in_sizes[2] : 0;
  const long long KD2 = (n_in > 3) ? (long long)in_sizes[3] : 0;
  const long long D   = (K > 0) ? KD / K : 0;
  const long long N   = (D > 0) ? ND / D : 0;

  const long long ws_floats = 16 + 2 * K + KD + 2 * N;  // slots = N u64 at tail

  float sig = 0.f;
  if (n_in != 4)                          sig = 1e4f * (float)n_in;
  else if (K <= 0 || KD % K != 0)         sig = 2.5e7f;
  else if (D != 64)                       sig = 1e7f + 1e4f * (float)D;
  else if (KD2 != KD)                     sig = 2e7f;
  else if (ND % 64 != 0 || N % 512 != 0)  sig = 3e7f;
  else if (K % 256 != 0)                  sig = 5e7f;
  else if ((long long)out_size != ND + 1 + N + K + 2 * KD)
                                          sig = (float)out_size;
  else if (ws_size < (size_t)ws_floats * sizeof(float))
                                          sig = 7e6f;
  if (sig != 0.f) { k_sig<<<1, 1, 0, stream>>>(o, sig); return; }

  u64* slots = (u64*)(ws + 16 + 2 * K + KD);      // 8-byte aligned offset
  const float lossmul = (float)(0.25 / (double)ND);

  hipMemsetAsync(ws, 0, (size_t)(16 + 2 * K + KD) * sizeof(float), stream);
  hipMemsetAsync(slots, 0xFF, (size_t)N * sizeof(u64), stream);
  k_prep<<<(int)(K / 256), 256, 0, stream>>>(cb, ecs, ws, (int)K);
  k_main<<<(int)(N / 64), 256, 0, stream>>>(z, cb, ws + WS_HDR, slots, (int)N, (int)K);
  k_post<<<(int)(N / 256), 256, 0, stream>>>(z, cb, slots, ws, o, (int)N, (int)K);
  k_fin<<<(int)(KD / 256), 256, 0, stream>>>(ecs, ees, ws, o, (int)N, (int)K, lossmul);
}

// Round 8
// 1400.181 us; speedup vs baseline: 1.3196x; 1.0358x over previous
//
#include <hip/hip_runtime.h>
#include <stdint.h>

typedef float4 __attribute__((may_alias)) float4a;
typedef unsigned int u32;
typedef unsigned long long u64;

// ws float layout: [0] loss, [1] sum(ema_cs),
// [16,16+K) e2 | [16+K,+K) counts | [16+2K,+K*64) emb sums | then N u64 slots
#define WS_LOSS 0
#define WS_SEMA 1
#define WS_HDR  16

__global__ void k_sig(float* o, float v) { o[0] = v; }

__device__ __forceinline__ float sq_nofuse(float x) {
  float p = x * x;
  __asm__("" : "+v"(p));   // block ffp-contract fusing (numpy rounds the square)
  return p;
}

// numpy pairwise_sum of squares, n=64 contiguous fp32: 8 accumulators + fixed
// combine tree, STREAMING (only ~16 live temps -> no spill).
__device__ __forceinline__ float z2_np64(const float* v) {
  float r0 = sq_nofuse(v[0]), r1 = sq_nofuse(v[1]);
  float r2 = sq_nofuse(v[2]), r3 = sq_nofuse(v[3]);
  float r4 = sq_nofuse(v[4]), r5 = sq_nofuse(v[5]);
  float r6 = sq_nofuse(v[6]), r7 = sq_nofuse(v[7]);
  #pragma unroll
  for (int i = 8; i < 64; i += 8) {
    r0 += sq_nofuse(v[i + 0]); r1 += sq_nofuse(v[i + 1]);
    r2 += sq_nofuse(v[i + 2]); r3 += sq_nofuse(v[i + 3]);
    r4 += sq_nofuse(v[i + 4]); r5 += sq_nofuse(v[i + 5]);
    r6 += sq_nofuse(v[i + 6]); r7 += sq_nofuse(v[i + 7]);
  }
  return ((r0 + r1) + (r2 + r3)) + ((r4 + r5) + (r6 + r7));
}

__global__ __launch_bounds__(256) void k_prep(const float* __restrict__ cb,
                                              const float* __restrict__ ecs,
                                              float* __restrict__ ws, int K) {
  const int k = blockIdx.x * 256 + threadIdx.x;   // grid covers exactly K rows
  const float* e = cb + ((size_t)k << 6);
  ws[WS_HDR + k] = z2_np64(e);                    // e2[k], np-fp32-exact

  float v = ecs[k];
  #pragma unroll
  for (int o = 32; o; o >>= 1) v += __shfl_xor(v, o, 64);
  if ((threadIdx.x & 63) == 0) atomicAdd(&ws[WS_SEMA], v);
}

// GEMM-fragment distance scan, 8x8 fragments. Block = 128 rows; K in shared
// 128-code tiles; 4 waves co-compute disjoint code ranges. Per j per lane:
// 4 ds_read_b128 -> 64 FMAs (16 FMA/load). Row fragment is two quads
// (4g.., 64+4g..) so z-reads pack a contiguous 256B span -> 2-way (free);
// e-reads hit 4 distinct bank-quads -> conflict-free.
__global__ __launch_bounds__(256) void k_main(const float* __restrict__ z,
                                              const float* __restrict__ cb,
                                              const float* __restrict__ e2s,
                                              u64* __restrict__ slots,
                                              int N, int K) {
  __shared__ float zT[64][128];        // zT[j][row]
  __shared__ float eb[64][128];        // eT[j][code]
  __shared__ float z2p[128][4];        // per-row np-tree partials s0..s3

  const int tid  = threadIdx.x;
  const int lane = tid & 63;
  const int w    = tid >> 6;
  const int g    = lane & 15;                     // row-quad group
  const int b8   = (((w << 2) | (lane >> 4)) << 3); // code-frag base 0..120
  const int rowbase = blockIdx.x * 128;
  const int nt   = K >> 7;                        // tiles of 128 codes

  // staging role: thread covers (column sc, j-half jh)
  const int sc = tid & 127;
  const int h  = tid >> 7;
  const int jh = h << 5;                          // 0 or 32

  // ---- prologue: stage zT (transposed) + z2 partials
  {
    const float4a* src = (const float4a*)(z + ((size_t)(rowbase + sc) << 6) + jh);
    float4 zs[8];
    #pragma unroll
    for (int i = 0; i < 8; ++i) zs[i] = src[i];
    #pragma unroll
    for (int i = 0; i < 8; ++i) {
      zT[jh + 4*i + 0][sc] = zs[i].x;
      zT[jh + 4*i + 1][sc] = zs[i].y;
      zT[jh + 4*i + 2][sc] = zs[i].z;
      zT[jh + 4*i + 3][sc] = zs[i].w;
    }
    // z2 partials: np-tree accumulators r_{4h..4h+3} -> s_{2h}, s_{2h+1};
    // final (s0+s1)+(s2+s3) reproduces z2_np64's combine tree bit-exactly.
    const float* vr = z + ((size_t)(rowbase + sc) << 6) + 4*h;
    float ra = sq_nofuse(vr[0]), rb = sq_nofuse(vr[1]);
    float rc = sq_nofuse(vr[2]), rd = sq_nofuse(vr[3]);
    #pragma unroll
    for (int i = 8; i < 64; i += 8) {
      ra += sq_nofuse(vr[i + 0]); rb += sq_nofuse(vr[i + 1]);
      rc += sq_nofuse(vr[i + 2]); rd += sq_nofuse(vr[i + 3]);
    }
    z2p[sc][2*h + 0] = ra + rb;
    z2p[sc][2*h + 1] = rc + rd;
  }

  // stage tile 0 of e into regs (HBM/L2 latency hidden under zT staging)
  float4 st[8];
  {
    const float4a* sp = (const float4a*)(cb + ((size_t)sc << 6) + jh);
    #pragma unroll
    for (int i = 0; i < 8; ++i) st[i] = sp[i];
  }

  __syncthreads();                                // zT, z2p visible

  // per-lane row constants: r<4 -> row 4g+r ; r>=4 -> row 64+4g+(r-4)
  float z2r[8];
  #pragma unroll
  for (int i = 0; i < 4; ++i) {
    { const float4 p = *(const float4a*)&z2p[4*g + i][0];
      z2r[i]     = (p.x + p.y) + (p.z + p.w); }
    { const float4 p = *(const float4a*)&z2p[64 + 4*g + i][0];
      z2r[4 + i] = (p.x + p.y) + (p.z + p.w); }
  }

  float best[8]; int bk[8];
  #pragma unroll
  for (int r = 0; r < 8; ++r) { best[r] = 3.0e38f; bk[r] = 0; }

  for (int t = 0; t < nt; ++t) {
    // write staged e tile (transposed) -> eb
    #pragma unroll
    for (int i = 0; i < 8; ++i) {
      eb[jh + 4*i + 0][sc] = st[i].x;
      eb[jh + 4*i + 1][sc] = st[i].y;
      eb[jh + 4*i + 2][sc] = st[i].z;
      eb[jh + 4*i + 3][sc] = st[i].w;
    }
    __syncthreads();                              // eb tile t ready

    if (t + 1 < nt) {                             // prefetch tile t+1 under compute
      const float4a* sp =
          (const float4a*)(cb + ((size_t)((t + 1) * 128 + sc) << 6) + jh);
      #pragma unroll
      for (int i = 0; i < 8; ++i) st[i] = sp[i];
    }
    const float4 e2lo = *(const float4a*)(e2s + t * 128 + b8);      // L2-hot
    const float4 e2hi = *(const float4a*)(e2s + t * 128 + b8 + 4);

    float acc[8][8];
    #pragma unroll
    for (int r = 0; r < 8; ++r)
      #pragma unroll
      for (int c = 0; c < 8; ++c) acc[r][c] = 0.f;

    #pragma unroll 4
    for (int j = 0; j < 64; ++j) {
      const float4 zl = *(const float4a*)&zT[j][4*g];
      const float4 zh = *(const float4a*)&zT[j][64 + 4*g];
      const float4 el = *(const float4a*)&eb[j][b8];
      const float4 eh = *(const float4a*)&eb[j][b8 + 4];
      const float zr[8] = {zl.x, zl.y, zl.z, zl.w, zh.x, zh.y, zh.z, zh.w};
      const float ec[8] = {el.x, el.y, el.z, el.w, eh.x, eh.y, eh.z, eh.w};
      #pragma unroll
      for (int r = 0; r < 8; ++r)
        #pragma unroll
        for (int c = 0; c < 8; ++c)   // ascending-j fma chain per (r,c) = np/BLAS
          acc[r][c] = __builtin_fmaf(ec[c], zr[r], acc[r][c]);
    }

    // selection: lane's codes ascend (c, then t) -> strict < = first-min-wins
    const float e2a[8] = {e2lo.x, e2lo.y, e2lo.z, e2lo.w,
                          e2hi.x, e2hi.y, e2hi.z, e2hi.w};
    const int kt = t * 128 + b8;
    #pragma unroll
    for (int c = 0; c < 8; ++c) {
      const float e2c = e2a[c];
      const int kk = kt + c;
      #pragma unroll
      for (int r = 0; r < 8; ++r) {
        const float d = __builtin_fmaf(-2.0f, acc[r][c], z2r[r] + e2c);
        if (d < best[r]) { best[r] = d; bk[r] = kk; }
      }
    }
    __syncthreads();                              // all reads of eb tile t done
  }

  // ---- cross-lane merge over the 4 code-groups (lanes g, g+16, g+32, g+48):
  // lexicographic (d, k): equal d -> smaller k (global first-min)
  #pragma unroll
  for (int off = 16; off <= 32; off <<= 1) {
    #pragma unroll
    for (int r = 0; r < 8; ++r) {
      const float pd = __shfl_xor(best[r], off, 64);
      const int   pk = __shfl_xor(bk[r], off, 64);
      if (pd < best[r] || (pd == best[r] && pk < bk[r])) { best[r] = pd; bk[r] = pk; }
    }
  }
  // ---- cross-wave merge via packed atomicMin (distances > 0)
  if (lane < 16) {
    #pragma unroll
    for (int r = 0; r < 8; ++r) {
      const int row = (r < 4) ? (4 * lane + r) : (64 + 4 * lane + (r - 4));
      atomicMin(&slots[rowbase + row],
                ((u64)__float_as_uint(best[r]) << 32) | (u32)bk[r]);
    }
  }
}

// epilogue: read winner, write index+quantized, loss, EMA scatter
__global__ __launch_bounds__(256) void k_post(const float* __restrict__ z,
                                              const float* __restrict__ cb,
                                              const u64* __restrict__ slots,
                                              float* __restrict__ ws,
                                              float* __restrict__ o,
                                              int N, int K) {
  const int r = blockIdx.x * 256 + threadIdx.x;
  const int bk = (int)(u32)(slots[r] & 0xFFFFFFFFull);
  const size_t base = (size_t)N << 6;
  o[base + 1 + (size_t)r] = (float)bk;

  const float4a* zr = (const float4a*)(z + ((size_t)r << 6));
  const float4a* qr = (const float4a*)(cb + ((size_t)bk << 6));
  float4a* dst = (float4a*)(o + ((size_t)r << 6));
  float zbuf[64];
  float lsum = 0.f;
  #pragma unroll
  for (int t = 0; t < 16; ++t) {
    const float4 zw = zr[t];
    const float4 qw = qr[t];
    float4 out;
    float d;
    d = zw.x - qw.x; lsum = __builtin_fmaf(d, d, lsum); out.x = zw.x + (qw.x - zw.x);
    d = zw.y - qw.y; lsum = __builtin_fmaf(d, d, lsum); out.y = zw.y + (qw.y - zw.y);
    d = zw.z - qw.z; lsum = __builtin_fmaf(d, d, lsum); out.z = zw.z + (qw.z - zw.z);
    d = zw.w - qw.w; lsum = __builtin_fmaf(d, d, lsum); out.w = zw.w + (qw.w - zw.w);
    dst[t] = out;
    zbuf[4*t] = zw.x; zbuf[4*t+1] = zw.y; zbuf[4*t+2] = zw.z; zbuf[4*t+3] = zw.w;
  }

  #pragma unroll
  for (int s = 32; s; s >>= 1) lsum += __shfl_xor(lsum, s, 64);
  if ((threadIdx.x & 63) == 0) atomicAdd(ws + WS_LOSS, lsum);

  atomicAdd(ws + WS_HDR + K + bk, 1.0f);
  float* emb = ws + WS_HDR + 2 * K + ((size_t)bk << 6);
  #pragma unroll
  for (int j = 0; j < 64; ++j) atomicAdd(emb + j, zbuf[j]);
}

__global__ __launch_bounds__(256) void k_fin(const float* __restrict__ ecs,
                                             const float* __restrict__ ees,
                                             const float* __restrict__ ws,
                                             float* __restrict__ o,
                                             int N, int K, float lossmul) {
  const int KD = K << 6;
  const int idx = blockIdx.x * 256 + threadIdx.x;
  if (idx >= KD) return;
  const int k = idx >> 6;
  const int j = idx & 63;
  const size_t base = (size_t)N << 6;

  const float n = 0.99f * ws[WS_SEMA] + 0.01f * (float)N;
  const float cs_new = 0.99f * ecs[k] + 0.01f * ws[WS_HDR + K + k];
  const float smoothed = (cs_new + 1e-5f) / (n + (float)K * 1e-5f) * n;
  const float es_new = 0.99f * ees[idx] + 0.01f * ws[WS_HDR + 2 * K + idx];

  const size_t es_base = base + 1 + (size_t)N + (size_t)K;
  o[es_base + (size_t)idx] = es_new;
  o[es_base + (size_t)KD + (size_t)idx] = es_new / smoothed;
  if (j == 0)   o[base + 1 + (size_t)N + (size_t)k] = cs_new;
  if (idx == 0) o[base] = ws[WS_LOSS] * lossmul;
}

extern "C" void kernel_launch(void* const* d_in, const int* in_sizes, int n_in,
                              void* d_out, int out_size, void* d_ws, size_t ws_size,
                              hipStream_t stream) {
  float* o = (float*)d_out;
  const float* z   = (const float*)d_in[0];
  const float* cb  = (const float*)d_in[1];
  const float* ecs = (const float*)d_in[2];
  const float* ees = (const float*)d_in[3];
  float* ws = (float*)d_ws;

  const long long ND  = (n_in > 0) ? (long long)in_sizes[0] : 0;
  const long long KD  = (n_in > 1) ? (long long)in_sizes[1] : 0;
  const long long K   = (n_in > 2) ? (long long)in_sizes[2] : 0;
  const long long KD2 = (n_in > 3) ? (long long)in_sizes[3] : 0;
  const long long D   = (K > 0) ? KD / K : 0;
  const long long N   = (D > 0) ? ND / D : 0;

  const long long ws_floats = 16 + 2 * K + KD + 2 * N;  // slots = N u64 at tail

  float sig = 0.f;
  if (n_in != 4)                          sig = 1e4f * (float)n_in;
  else if (K <= 0 || KD % K != 0)         sig = 2.5e7f;
  else if (D != 64)                       sig = 1e7f + 1e4f * (float)D;
  else if (KD2 != KD)                     sig = 2e7f;
  else if (ND % 64 != 0 || N % 512 != 0)  sig = 3e7f;
  else if (K % 256 != 0)                  sig = 5e7f;
  else if ((long long)out_size != ND + 1 + N + K + 2 * KD)
                                          sig = (float)out_size;
  else if (ws_size < (size_t)ws_floats * sizeof(float))
                                          sig = 7e6f;
  if (sig != 0.f) { k_sig<<<1, 1, 0, stream>>>(o, sig); return; }

  u64* slots = (u64*)(ws + 16 + 2 * K + KD);      // 8-byte aligned offset
  const float lossmul = (float)(0.25 / (double)ND);

  hipMemsetAsync(ws, 0, (size_t)(16 + 2 * K + KD) * sizeof(float), stream);
  hipMemsetAsync(slots, 0xFF, (size_t)N * sizeof(u64), stream);
  k_prep<<<(int)(K / 256), 256, 0, stream>>>(cb, ecs, ws, (int)K);
  k_main<<<(int)(N / 128), 256, 0, stream>>>(z, cb, ws + WS_HDR, slots, (int)N, (int)K);
  k_post<<<(int)(N / 256), 256, 0, stream>>>(z, cb, slots, ws, o, (int)N, (int)K);
  k_fin<<<(int)(KD / 256), 256, 0, stream>>>(ecs, ees, ws, o, (int)N, (int)K, lossmul);
}

// Round 9
// 1382.123 us; speedup vs baseline: 1.3369x; 1.0131x over previous
//
#include <hip/hip_runtime.h>
#include <stdint.h>

typedef float4 __attribute__((may_alias)) float4a;
typedef unsigned int u32;
typedef unsigned long long u64;

// ws float layout: [0] loss, [1] sum(ema_cs),
// [16,16+K) e2 | [16+K,+K) counts | [16+2K,+K*64) emb sums | then N u64 slots
#define WS_LOSS 0
#define WS_SEMA 1
#define WS_HDR  16

__global__ void k_sig(float* o, float v) { o[0] = v; }

__device__ __forceinline__ float sq_nofuse(float x) {
  float p = x * x;
  __asm__("" : "+v"(p));   // block ffp-contract fusing (numpy rounds the square)
  return p;
}

// numpy pairwise_sum of squares, n=64 contiguous fp32: 8 accumulators + fixed
// combine tree, STREAMING (only ~16 live temps -> no spill).
__device__ __forceinline__ float z2_np64(const float* v) {
  float r0 = sq_nofuse(v[0]), r1 = sq_nofuse(v[1]);
  float r2 = sq_nofuse(v[2]), r3 = sq_nofuse(v[3]);
  float r4 = sq_nofuse(v[4]), r5 = sq_nofuse(v[5]);
  float r6 = sq_nofuse(v[6]), r7 = sq_nofuse(v[7]);
  #pragma unroll
  for (int i = 8; i < 64; i += 8) {
    r0 += sq_nofuse(v[i + 0]); r1 += sq_nofuse(v[i + 1]);
    r2 += sq_nofuse(v[i + 2]); r3 += sq_nofuse(v[i + 3]);
    r4 += sq_nofuse(v[i + 4]); r5 += sq_nofuse(v[i + 5]);
    r6 += sq_nofuse(v[i + 6]); r7 += sq_nofuse(v[i + 7]);
  }
  return ((r0 + r1) + (r2 + r3)) + ((r4 + r5) + (r6 + r7));
}

__global__ __launch_bounds__(256) void k_prep(const float* __restrict__ cb,
                                              const float* __restrict__ ecs,
                                              float* __restrict__ ws, int K) {
  const int k = blockIdx.x * 256 + threadIdx.x;   // grid covers exactly K rows
  const float* e = cb + ((size_t)k << 6);
  ws[WS_HDR + k] = z2_np64(e);                    // e2[k], np-fp32-exact

  float v = ecs[k];
  #pragma unroll
  for (int o = 32; o; o >>= 1) v += __shfl_xor(v, o, 64);
  if ((threadIdx.x & 63) == 0) atomicAdd(&ws[WS_SEMA], v);
}

// GEMM-fragment distance scan, 8x16 fragments over 256-code passes with the
// j-dimension split in 32-j halves. Per j per lane: 6 ds_read_b128 -> 128 FMAs
// (LDS demand 96 B/cyc at full VALU < 128 peak -> VALU-bound, off the R8 knife
// edge). All LDS access 2-way-or-free bank patterns. acc chains are ascending-j
// j=0..63 across the two halves = bit-identical to np/BLAS order.
__global__ __launch_bounds__(256) void k_main(const float* __restrict__ z,
                                              const float* __restrict__ cb,
                                              const float* __restrict__ e2s,
                                              u64* __restrict__ slots,
                                              int N, int K) {
  __shared__ float zT[64][128];        // zT[j][row], staged once
  __shared__ float eb[32][256];        // eT[j-half][code], staged per half
  __shared__ float z2p[128][4];        // per-row np-tree partials s0..s3

  const int tid  = threadIdx.x;
  const int lane = tid & 63;
  const int w    = tid >> 6;
  const int g    = lane & 15;                 // row-quad group
  const int cg   = lane >> 4;                 // code-group within wave
  const int cbase = (w << 6) + (cg << 4);     // code base within pass (0..240)
  const int rowbase = blockIdx.x * 128;
  const int npass = K >> 8;                   // passes of 256 codes

  // ---- prologue: stage zT (transposed) + z2 partials (R8-verified pattern)
  {
    const int sc = tid & 127;
    const int h  = tid >> 7;
    const int jh = h << 5;
    const float4a* src = (const float4a*)(z + ((size_t)(rowbase + sc) << 6) + jh);
    float4 zs[8];
    #pragma unroll
    for (int i = 0; i < 8; ++i) zs[i] = src[i];
    #pragma unroll
    for (int i = 0; i < 8; ++i) {
      zT[jh + 4*i + 0][sc] = zs[i].x;
      zT[jh + 4*i + 1][sc] = zs[i].y;
      zT[jh + 4*i + 2][sc] = zs[i].z;
      zT[jh + 4*i + 3][sc] = zs[i].w;
    }
    // z2 partials: np-tree accumulators r_{4h..4h+3} -> s_{2h}, s_{2h+1};
    // final (s0+s1)+(s2+s3) reproduces z2_np64's combine tree bit-exactly.
    const float* vr = z + ((size_t)(rowbase + sc) << 6) + 4*h;
    float ra = sq_nofuse(vr[0]), rb = sq_nofuse(vr[1]);
    float rc = sq_nofuse(vr[2]), rd = sq_nofuse(vr[3]);
    #pragma unroll
    for (int i = 8; i < 64; i += 8) {
      ra += sq_nofuse(vr[i + 0]); rb += sq_nofuse(vr[i + 1]);
      rc += sq_nofuse(vr[i + 2]); rd += sq_nofuse(vr[i + 3]);
    }
    z2p[sc][2*h + 0] = ra + rb;
    z2p[sc][2*h + 1] = rc + rd;
  }
  __syncthreads();                            // zT, z2p visible

  // per-lane row constants: r<4 -> row 4g+r ; r>=4 -> row 64+4g+(r-4)
  float z2r[8];
  #pragma unroll
  for (int i = 0; i < 4; ++i) {
    { const float4 p = *(const float4a*)&z2p[4*g + i][0];
      z2r[i]     = (p.x + p.y) + (p.z + p.w); }
    { const float4 p = *(const float4a*)&z2p[64 + 4*g + i][0];
      z2r[4 + i] = (p.x + p.y) + (p.z + p.w); }
  }

  float best[8]; int bk[8];
  #pragma unroll
  for (int r = 0; r < 8; ++r) { best[r] = 3.0e38f; bk[r] = 0; }

  for (int p = 0; p < npass; ++p) {
    float acc[8][16];
    #pragma unroll
    for (int r = 0; r < 8; ++r)
      #pragma unroll
      for (int c = 0; c < 16; ++c) acc[r][c] = 0.f;

    #pragma unroll 1
    for (int half = 0; half < 2; ++half) {
      // stage-loads issued BEFORE the barrier: HBM/L2 latency hides under the
      // previous half's compute (T14 split). Thread covers code p*256+tid.
      float4 s[8];
      {
        const float4a* sp =
            (const float4a*)(cb + ((size_t)((p << 8) + tid) << 6) + (half << 5));
        #pragma unroll
        for (int i = 0; i < 8; ++i) s[i] = sp[i];
      }
      __syncthreads();                        // all waves done reading eb
      #pragma unroll
      for (int i = 0; i < 8; ++i) {           // transposed write, 2-way banks
        eb[4*i + 0][tid] = s[i].x;
        eb[4*i + 1][tid] = s[i].y;
        eb[4*i + 2][tid] = s[i].z;
        eb[4*i + 3][tid] = s[i].w;
      }
      __syncthreads();                        // eb half ready

      const int jb = half << 5;
      #pragma unroll 2
      for (int jj = 0; jj < 32; ++jj) {
        const float4 zl = *(const float4a*)&zT[jb + jj][4*g];
        const float4 zh = *(const float4a*)&zT[jb + jj][64 + 4*g];
        const float4 e0 = *(const float4a*)&eb[jj][cbase];
        const float4 e1 = *(const float4a*)&eb[jj][cbase + 4];
        const float4 e2f = *(const float4a*)&eb[jj][cbase + 8];
        const float4 e3 = *(const float4a*)&eb[jj][cbase + 12];
        const float zr[8]  = {zl.x, zl.y, zl.z, zl.w, zh.x, zh.y, zh.z, zh.w};
        const float ec[16] = {e0.x, e0.y, e0.z, e0.w, e1.x, e1.y, e1.z, e1.w,
                              e2f.x, e2f.y, e2f.z, e2f.w, e3.x, e3.y, e3.z, e3.w};
        #pragma unroll
        for (int r = 0; r < 8; ++r)
          #pragma unroll
          for (int c = 0; c < 16; ++c)  // ascending-j fma chain per (r,c)
            acc[r][c] = __builtin_fmaf(ec[c], zr[r], acc[r][c]);
      }
    }

    // selection once per 256-code pass: lane's codes ascend (c, then p)
    // -> strict < = first-min-wins
    const float4a* e2p4 = (const float4a*)(e2s + (p << 8) + cbase);
    const float4 q0 = e2p4[0], q1 = e2p4[1], q2 = e2p4[2], q3 = e2p4[3];
    const float e2a[16] = {q0.x, q0.y, q0.z, q0.w, q1.x, q1.y, q1.z, q1.w,
                           q2.x, q2.y, q2.z, q2.w, q3.x, q3.y, q3.z, q3.w};
    const int kt = (p << 8) + cbase;
    #pragma unroll
    for (int c = 0; c < 16; ++c) {
      const float e2c = e2a[c];
      const int kk = kt + c;
      #pragma unroll
      for (int r = 0; r < 8; ++r) {
        const float d = __builtin_fmaf(-2.0f, acc[r][c], z2r[r] + e2c);
        if (d < best[r]) { best[r] = d; bk[r] = kk; }
      }
    }
  }

  // ---- cross-lane merge over the 4 code-groups (lanes g, g+16, g+32, g+48):
  // lexicographic (d, k): equal d -> smaller k (global first-min)
  #pragma unroll
  for (int off = 16; off <= 32; off <<= 1) {
    #pragma unroll
    for (int r = 0; r < 8; ++r) {
      const float pd = __shfl_xor(best[r], off, 64);
      const int   pk = __shfl_xor(bk[r], off, 64);
      if (pd < best[r] || (pd == best[r] && pk < bk[r])) { best[r] = pd; bk[r] = pk; }
    }
  }
  // ---- cross-wave merge via packed atomicMin (distances > 0)
  if (lane < 16) {
    #pragma unroll
    for (int r = 0; r < 8; ++r) {
      const int row = (r < 4) ? (4 * lane + r) : (64 + 4 * lane + (r - 4));
      atomicMin(&slots[rowbase + row],
                ((u64)__float_as_uint(best[r]) << 32) | (u32)bk[r]);
    }
  }
}

// epilogue: read winner, write index+quantized, loss, EMA scatter
__global__ __launch_bounds__(256) void k_post(const float* __restrict__ z,
                                              const float* __restrict__ cb,
                                              const u64* __restrict__ slots,
                                              float* __restrict__ ws,
                                              float* __restrict__ o,
                                              int N, int K) {
  const int r = blockIdx.x * 256 + threadIdx.x;
  const int bk = (int)(u32)(slots[r] & 0xFFFFFFFFull);
  const size_t base = (size_t)N << 6;
  o[base + 1 + (size_t)r] = (float)bk;

  const float4a* zr = (const float4a*)(z + ((size_t)r << 6));
  const float4a* qr = (const float4a*)(cb + ((size_t)bk << 6));
  float4a* dst = (float4a*)(o + ((size_t)r << 6));
  float zbuf[64];
  float lsum = 0.f;
  #pragma unroll
  for (int t = 0; t < 16; ++t) {
    const float4 zw = zr[t];
    const float4 qw = qr[t];
    float4 out;
    float d;
    d = zw.x - qw.x; lsum = __builtin_fmaf(d, d, lsum); out.x = zw.x + (qw.x - zw.x);
    d = zw.y - qw.y; lsum = __builtin_fmaf(d, d, lsum); out.y = zw.y + (qw.y - zw.y);
    d = zw.z - qw.z; lsum = __builtin_fmaf(d, d, lsum); out.z = zw.z + (qw.z - zw.z);
    d = zw.w - qw.w; lsum = __builtin_fmaf(d, d, lsum); out.w = zw.w + (qw.w - zw.w);
    dst[t] = out;
    zbuf[4*t] = zw.x; zbuf[4*t+1] = zw.y; zbuf[4*t+2] = zw.z; zbuf[4*t+3] = zw.w;
  }

  #pragma unroll
  for (int s = 32; s; s >>= 1) lsum += __shfl_xor(lsum, s, 64);
  if ((threadIdx.x & 63) == 0) atomicAdd(ws + WS_LOSS, lsum);

  atomicAdd(ws + WS_HDR + K + bk, 1.0f);
  float* emb = ws + WS_HDR + 2 * K + ((size_t)bk << 6);
  #pragma unroll
  for (int j = 0; j < 64; ++j) atomicAdd(emb + j, zbuf[j]);
}

__global__ __launch_bounds__(256) void k_fin(const float* __restrict__ ecs,
                                             const float* __restrict__ ees,
                                             const float* __restrict__ ws,
                                             float* __restrict__ o,
                                             int N, int K, float lossmul) {
  const int KD = K << 6;
  const int idx = blockIdx.x * 256 + threadIdx.x;
  if (idx >= KD) return;
  const int k = idx >> 6;
  const int j = idx & 63;
  const size_t base = (size_t)N << 6;

  const float n = 0.99f * ws[WS_SEMA] + 0.01f * (float)N;
  const float cs_new = 0.99f * ecs[k] + 0.01f * ws[WS_HDR + K + k];
  const float smoothed = (cs_new + 1e-5f) / (n + (float)K * 1e-5f) * n;
  const float es_new = 0.99f * ees[idx] + 0.01f * ws[WS_HDR + 2 * K + idx];

  const size_t es_base = base + 1 + (size_t)N + (size_t)K;
  o[es_base + (size_t)idx] = es_new;
  o[es_base + (size_t)KD + (size_t)idx] = es_new / smoothed;
  if (j == 0)   o[base + 1 + (size_t)N + (size_t)k] = cs_new;
  if (idx == 0) o[base] = ws[WS_LOSS] * lossmul;
}

extern "C" void kernel_launch(void* const* d_in, const int* in_sizes, int n_in,
                              void* d_out, int out_size, void* d_ws, size_t ws_size,
                              hipStream_t stream) {
  float* o = (float*)d_out;
  const float* z   = (const float*)d_in[0];
  const float* cb  = (const float*)d_in[1];
  const float* ecs = (const float*)d_in[2];
  const float* ees = (const float*)d_in[3];
  float* ws = (float*)d_ws;

  const long long ND  = (n_in > 0) ? (long long)in_sizes[0] : 0;
  const long long KD  = (n_in > 1) ? (long long)in_sizes[1] : 0;
  const long long K   = (n_in > 2) ? (long long)in_sizes[2] : 0;
  const long long KD2 = (n_in > 3) ? (long long)in_sizes[3] : 0;
  const long long D   = (K > 0) ? KD / K : 0;
  const long long N   = (D > 0) ? ND / D : 0;

  const long long ws_floats = 16 + 2 * K + KD + 2 * N;  // slots = N u64 at tail

  float sig = 0.f;
  if (n_in != 4)                          sig = 1e4f * (float)n_in;
  else if (K <= 0 || KD % K != 0)         sig = 2.5e7f;
  else if (D != 64)                       sig = 1e7f + 1e4f * (float)D;
  else if (KD2 != KD)                     sig = 2e7f;
  else if (ND % 64 != 0 || N % 512 != 0)  sig = 3e7f;
  else if (K % 256 != 0)                  sig = 5e7f;
  else if ((long long)out_size != ND + 1 + N + K + 2 * KD)
                                          sig = (float)out_size;
  else if (ws_size < (size_t)ws_floats * sizeof(float))
                                          sig = 7e6f;
  if (sig != 0.f) { k_sig<<<1, 1, 0, stream>>>(o, sig); return; }

  u64* slots = (u64*)(ws + 16 + 2 * K + KD);      // 8-byte aligned offset
  const float lossmul = (float)(0.25 / (double)ND);

  hipMemsetAsync(ws, 0, (size_t)(16 + 2 * K + KD) * sizeof(float), stream);
  hipMemsetAsync(slots, 0xFF, (size_t)N * sizeof(u64), stream);
  k_prep<<<(int)(K / 256), 256, 0, stream>>>(cb, ecs, ws, (int)K);
  k_main<<<(int)(N / 128), 256, 0, stream>>>(z, cb, ws + WS_HDR, slots, (int)N, (int)K);
  k_post<<<(int)(N / 256), 256, 0, stream>>>(z, cb, slots, ws, o, (int)N, (int)K);
  k_fin<<<(int)(KD / 256), 256, 0, stream>>>(ecs, ees, ws, o, (int)N, (int)K, lossmul);
}